// Round 13
// baseline (165.391 us; speedup 1.0000x reference)
//
#include <hip/hip_runtime.h>
#include <cstddef>
#include <math.h>

#define BD 8
#define TD 256
#define SD 256
#define HD 512
#define K2F 2.885390081777927f    // 2*log2(e): arg of exp2 for e^(2x)

#define EXP2(x) __builtin_amdgcn_exp2f(x)
#define RCP(x)  __builtin_amdgcn_rcpf(x)

typedef __attribute__((ext_vector_type(8))) _Float16 half8;
typedef __attribute__((ext_vector_type(4))) float float4v;

// exp2 with arg clamped so E in [2^-80, 2^80]: products overflow to inf -> rcp -> 0,
// underflow to 0 -> r = 1; no inf*0 NaN path possible.
__device__ __forceinline__ float exp2_sat(float x) {
    return EXP2(fminf(fmaxf(x, -80.0f), 80.0f));
}

__device__ __forceinline__ half8 to_h8(float4 lo, float4 hi) {
    half8 h;
    h[0]=(_Float16)lo.x; h[1]=(_Float16)lo.y; h[2]=(_Float16)lo.z; h[3]=(_Float16)lo.w;
    h[4]=(_Float16)hi.x; h[5]=(_Float16)hi.y; h[6]=(_Float16)hi.z; h[7]=(_Float16)hi.w;
    return h;
}

// ---------------- proj: barrier-free fragment-direct fp16 MFMA ----------------
// 2048 blocks x 256 thr (8 blocks/CU, 32 waves/CU). Wave owns one 16x16 C tile.
// Block covers 64 m-rows (one quad) x 16 n-cols. XCD swizzle: bid&7 (presumed XCD)
// selects the m-quad residue class so same-XCD blocks share A rows in their L2.
// Stacked rows: 0..2047 = enc -> encT (B,H,S) = E_e;  2048..4095 = qry -> qryf = E_q.
__global__ __launch_bounds__(256) void proj_kernel(
    const float* __restrict__ enc, const float* __restrict__ qry,
    const float* __restrict__ Wh,  const float* __restrict__ Ws,
    float* __restrict__ encT, float* __restrict__ qryf)
{
    const int bid = blockIdx.x;          // 0..2047
    const int tid = threadIdx.x;         // 0..255
    const int l   = tid & 63;
    const int w   = tid >> 6;            // wave 0..3
    const int rf  = l & 15;
    const int q   = l >> 4;

    const int x  = bid & 7;              // presumed XCD id (round-robin dispatch)
    const int g  = bid >> 3;             // 0..255
    const int mq = x + 8 * (g >> 5);     // m-quad 0..63; same-XCD blocks share quads
    const int n0 = (g & 31) * 16;        // n-tile

    const int srow0 = mq * 64 + w * 16;  // stacked row base of this wave's tile
    const bool isq = srow0 >= 2048;

    const float* Arow = (isq ? qry + (size_t)(srow0 - 2048 + rf) * HD
                             : enc + (size_t)(srow0 + rf) * HD) + q * 8;
    const float* Brow = (isq ? Ws : Wh) + (size_t)(n0 + rf) * HD + q * 8;

    float4v acc = {0, 0, 0, 0};

    #pragma unroll 4
    for (int ks = 0; ks < 16; ++ks) {
        const int k0 = ks * 32;
        float4 al = *(const float4*)(Arow + k0);
        float4 ah = *(const float4*)(Arow + k0 + 4);
        float4 bl = *(const float4*)(Brow + k0);
        float4 bh = *(const float4*)(Brow + k0 + 4);
        half8 ha = to_h8(al, ah);
        half8 hb = to_h8(bl, bh);
        acc = __builtin_amdgcn_mfma_f32_16x16x32_f16(ha, hb, acc, 0, 0, 0);
    }

    // Epilogue (R12-validated C map: m-local = q*4 + r, n-local = rf).
    if (!isq) {
        const int b  = srow0 >> 8;
        const int sb = (srow0 & 255) + q * 4;
        float4 o = make_float4(exp2_sat(acc[0]*K2F), exp2_sat(acc[1]*K2F),
                               exp2_sat(acc[2]*K2F), exp2_sat(acc[3]*K2F));
        *(float4*)(encT + (size_t)b * HD * SD + (size_t)(n0 + rf) * SD + sb) = o;
    } else {
        const int mrow = (srow0 - 2048) + q * 4;
        #pragma unroll
        for (int r = 0; r < 4; ++r)
            qryf[(size_t)(mrow + r) * HD + n0 + rf] = exp2_sat(acc[r] * K2F);
    }
}

// ---------------- attn: proven R7 structure + XCD batch swizzle ----------------
// r = 1/(1 + E_e*E_q); wave owns j-slice, computes all 4 t per e-load.
__global__ __launch_bounds__(512) void attn_kernel(
    const float* __restrict__ enc,     // (B,S,H) raw
    const float* __restrict__ encT,    // (B,H,S) E_e
    const float* __restrict__ qryf,    // (B,T,H) E_q
    const float* __restrict__ v,       // (H)
    const int*   __restrict__ lens,    // (B)
    float* __restrict__ out)           // (B,T,H)
{
    __shared__ float qls[HD * 4];      // [j][t]  8 KB (E_q)
    __shared__ float pls[8 * 4 * 256]; // [w][t][s] partials 32 KB; aliased avred
    __shared__ float wls[4 * SD];      // [t][s] weights 4 KB

    const int blk = blockIdx.x;        // 0..511
    const int b   = blk & 7;           // batch = presumed XCD id -> L2 locality
    const int t0  = (blk >> 3) * 4;    // t-group 0..63 -> t0
    const int tid = threadIdx.x;
    const int w   = tid >> 6;          // wave 0..7
    const int l   = tid & 63;

    {   // stage E_q transposed: qls[j*4+t]
        const float* qf = qryf + ((size_t)b * TD + t0) * HD;
        float4 qv;
        qv.x = qf[0 * HD + tid]; qv.y = qf[1 * HD + tid];
        qv.z = qf[2 * HD + tid]; qv.w = qf[3 * HD + tid];
        *(float4*)&qls[tid * 4] = qv;
    }
    __syncthreads();

    // ---- scores: wave w covers j in [w*64, w*64+64); lane owns s = 4l..4l+3 ----
    float a[4][4];
    #pragma unroll
    for (int t = 0; t < 4; ++t)
        #pragma unroll
        for (int c = 0; c < 4; ++c) a[t][c] = 0.0f;
    {
        const float* ep = encT + (size_t)b * HD * SD + (size_t)(w * 64) * SD + l * 4;
        const int jbase = w * 64;
        #pragma unroll 4
        for (int jj = 0; jj < 64; ++jj) {
            float4 e = *(const float4*)(ep + (size_t)jj * SD);  // E_e, coalesced
            float4 q4 = *(const float4*)&qls[(jbase + jj) * 4]; // E_q, broadcast
            float vj = v[jbase + jj];
            float ev[4] = {e.x, e.y, e.z, e.w};
            float qv[4] = {q4.x, q4.y, q4.z, q4.w};
            #pragma unroll
            for (int t = 0; t < 4; ++t)
                #pragma unroll
                for (int c = 0; c < 4; ++c) {
                    float p = fmaf(ev[c], qv[t], 1.0f);
                    a[t][c] = fmaf(vj, RCP(p), a[t][c]);
                }
        }
    }
    #pragma unroll
    for (int t = 0; t < 4; ++t)
        *(float4*)&pls[(w * 4 + t) * 256 + l * 4] = make_float4(a[t][0], a[t][1], a[t][2], a[t][3]);
    __syncthreads();

    // ---- combine 8 j-slices + masked softmax: wave t<4 handles t; lane owns 4 s ----
    if (w < 4) {
        const int t = w;
        float p[4] = {0, 0, 0, 0};
        #pragma unroll
        for (int g = 0; g < 8; ++g) {
            float4 pp = *(const float4*)&pls[(g * 4 + t) * 256 + l * 4];
            p[0] += pp.x; p[1] += pp.y; p[2] += pp.z; p[3] += pp.w;
        }
        const int len = lens[b];
        const int s0 = l * 4;
        float sc[4];
        #pragma unroll
        for (int c = 0; c < 4; ++c)
            sc[c] = (s0 + c < len) ? -2.0f * p[c] : -INFINITY;
        float mx = fmaxf(fmaxf(sc[0], sc[1]), fmaxf(sc[2], sc[3]));
        #pragma unroll
        for (int off = 32; off; off >>= 1) mx = fmaxf(mx, __shfl_xor(mx, off));
        float ex[4]; float sum = 0.0f;
        #pragma unroll
        for (int c = 0; c < 4; ++c) { ex[c] = __expf(sc[c] - mx); sum += ex[c]; }
        #pragma unroll
        for (int off = 32; off; off >>= 1) sum += __shfl_xor(sum, off);
        const float inv = RCP(sum);
        *(float4*)&wls[t * SD + s0] = make_float4(ex[0]*inv, ex[1]*inv, ex[2]*inv, ex[3]*inv);
    }
    __syncthreads();

    // ---- AV: thread owns (h-float4, s-slice g); accumulates all 4 t ----
    const int g  = tid >> 7;           // s-slice 0..3 (wave-uniform)
    const int h4 = (tid & 127) * 4;
    float* avred = pls;
    {
        const float* eb = enc + (size_t)b * SD * HD + h4;
        float4 o[4] = {{0,0,0,0},{0,0,0,0},{0,0,0,0},{0,0,0,0}};
        #pragma unroll 2
        for (int ss = 0; ss < 64; ++ss) {
            const int s = g * 64 + ss;
            float4 evv = *(const float4*)(eb + (size_t)s * HD);
            float wt[4];
            #pragma unroll
            for (int t = 0; t < 4; ++t) wt[t] = wls[t * SD + s];
            #pragma unroll
            for (int t = 0; t < 4; ++t) {
                o[t].x = fmaf(wt[t], evv.x, o[t].x);
                o[t].y = fmaf(wt[t], evv.y, o[t].y);
                o[t].z = fmaf(wt[t], evv.z, o[t].z);
                o[t].w = fmaf(wt[t], evv.w, o[t].w);
            }
        }
        #pragma unroll
        for (int t = 0; t < 4; ++t)
            *(float4*)&avred[(size_t)(g * 4 + t) * 512 + h4] = o[t];
    }
    __syncthreads();

    // final cross-slice reduce + store: thread owns (t = tid>>7, h-float4)
    {
        const int t  = tid >> 7;
        const int hh = (tid & 127) * 4;
        float4 r = {0, 0, 0, 0};
        #pragma unroll
        for (int gg = 0; gg < 4; ++gg) {
            float4 xx = *(const float4*)&avred[(size_t)(gg * 4 + t) * 512 + hh];
            r.x += xx.x; r.y += xx.y; r.z += xx.z; r.w += xx.w;
        }
        *(float4*)(out + ((size_t)b * TD + t0 + t) * HD + hh) = r;
    }
}

extern "C" void kernel_launch(void* const* d_in, const int* in_sizes, int n_in,
                              void* d_out, int out_size, void* d_ws, size_t ws_size,
                              hipStream_t stream) {
    const float* query = (const float*)d_in[0];
    const float* enc   = (const float*)d_in[1];
    const int*   lens  = (const int*)d_in[2];
    const float* W_h   = (const float*)d_in[3];
    const float* W_s   = (const float*)d_in[4];
    const float* v     = (const float*)d_in[5];
    float* out = (float*)d_out;

    char* ws = (char*)d_ws;
    float* encT = (float*)(ws);                       // 4 MB (B,H,S)  E_e
    float* qryf = (float*)(ws + ((size_t)4 << 20));   // 4 MB (B,T,H)  E_q

    proj_kernel<<<2048, 256, 0, stream>>>(enc, query, W_h, W_s, encT, qryf);
    attn_kernel<<<512, 512, 0, stream>>>(enc, encT, qryf, v, lens, out);
}

// Round 14
// 122.057 us; speedup vs baseline: 1.3550x; 1.3550x over previous
//
#include <hip/hip_runtime.h>
#include <cstddef>
#include <math.h>

#define BD 8
#define TD 256
#define SD 256
#define HD 512
#define K2F 2.885390081777927f    // 2*log2(e): arg of exp2 for e^(2x)

#define EXP2(x) __builtin_amdgcn_exp2f(x)
#define RCP(x)  __builtin_amdgcn_rcpf(x)

typedef __attribute__((ext_vector_type(8))) _Float16 half8;
typedef __attribute__((ext_vector_type(4))) _Float16 half4;
typedef __attribute__((ext_vector_type(4))) float float4v;

// exp2 with arg clamped so E in [2^-80, 2^80]: products overflow to inf -> rcp -> 0,
// underflow to 0 -> r = 1; no inf*0 NaN path possible.
__device__ __forceinline__ float exp2_sat(float x) {
    return EXP2(fminf(fmaxf(x, -80.0f), 80.0f));
}

// ---------------- pack: fp32 -> fp16 in MFMA-fragment order ----------------
// pk[tile][ks][lane][j] = M[tile*16 + (lane&15)][ks*32 + (lane>>4)*8 + j]
// One block per 16-row tile (32 KB contiguous source). Reads AND writes are
// contiguous 1KB wave-accesses; the permutation happens through LDS.
#define CSTR 536   // LDS row stride in halves (1072 B) — spreads b128 read banks
__global__ __launch_bounds__(256) void pack_kernel(
    const float* __restrict__ enc, const float* __restrict__ qry,
    const float* __restrict__ Wh,  const float* __restrict__ Ws,
    _Float16* __restrict__ Apk,    // 256 tiles (enc 0..127, qry 128..255)
    _Float16* __restrict__ Bpk)    // 64 tiles (Wh 0..31, Ws 32..63)
{
    __shared__ _Float16 lds[16 * CSTR];   // ~16.8 KB

    const int bid = blockIdx.x;          // 0..319
    const int tid = threadIdx.x;

    const float* src;
    _Float16* dst;
    if (bid < 128)      { src = enc + (size_t)bid * 16 * HD;         dst = Apk + (size_t)bid * 8192; }
    else if (bid < 256) { src = qry + (size_t)(bid - 128) * 16 * HD; dst = Apk + (size_t)bid * 8192; }
    else if (bid < 288) { src = Wh  + (size_t)(bid - 256) * 16 * HD; dst = Bpk + (size_t)(bid - 256) * 8192; }
    else                { src = Ws  + (size_t)(bid - 288) * 16 * HD; dst = Bpk + (size_t)(bid - 256) * 8192; }

    // load 8192 floats (1KB contiguous per wave-inst), convert, store to LDS
    #pragma unroll
    for (int i = 0; i < 8; ++i) {
        const int flat = i * 1024 + tid * 4;
        float4 x = *(const float4*)(src + flat);
        const int row = flat >> 9, col = flat & 511;
        half4 h;
        h[0]=(_Float16)x.x; h[1]=(_Float16)x.y; h[2]=(_Float16)x.z; h[3]=(_Float16)x.w;
        *(half4*)&lds[row * CSTR + col] = h;
    }
    __syncthreads();

    // write 1024 16B-runs in fragment order (1KB contiguous per wave-inst)
    #pragma unroll
    for (int j = 0; j < 4; ++j) {
        const int r  = j * 256 + tid;    // 0..1023
        const int ks = r >> 6, l = r & 63;
        const int rf = l & 15, q = l >> 4;
        half8 h = *(const half8*)&lds[rf * CSTR + ks * 32 + q * 8];
        *(half8*)(dst + (size_t)r * 8) = h;
    }
}

// ---------------- proj: fragment-direct MFMA, all loads 1KB-contiguous ----------------
// 1024 blocks x 256 thr (4 blocks/CU). Block: 8 m-tiles x 1 n-tile; wave w owns
// m-tiles mg*8 + w*2 + {0,1}. No LDS, no barriers.
__global__ __launch_bounds__(256) void proj_kernel(
    const _Float16* __restrict__ Apk, const _Float16* __restrict__ Bpk,
    float* __restrict__ encT, float* __restrict__ qryf)
{
    const int bid = blockIdx.x;          // 0..1023
    const int tid = threadIdx.x;
    const int l   = tid & 63;
    const int w   = tid >> 6;            // wave 0..3
    const int rf  = l & 15;
    const int q   = l >> 4;

    const int nt = bid & 31;             // n-tile 0..31
    const int mg = bid >> 5;             // m-group 0..31
    const int mt0 = mg * 8 + w * 2;      // m-tiles (0..255)
    const int mt1 = mt0 + 1;

    const _Float16* A0 = Apk + (size_t)mt0 * 8192 + l * 8;
    const _Float16* A1 = Apk + (size_t)mt1 * 8192 + l * 8;
    const _Float16* Bp = Bpk + (size_t)(((mt0 >= 128) ? 32 : 0) + (nt >> 1) * 2 + (nt & 1)) * 8192 + l * 8;
    // note: B tile index = (isq? 32:0) + nt  (written explicitly below for clarity)

    float4v acc0 = {0,0,0,0}, acc1 = {0,0,0,0};

    #pragma unroll 4
    for (int ks = 0; ks < 16; ++ks) {
        half8 a0 = *(const half8*)(A0 + (size_t)ks * 512);
        half8 a1 = *(const half8*)(A1 + (size_t)ks * 512);
        half8 b  = *(const half8*)(Bp + (size_t)ks * 512);
        acc0 = __builtin_amdgcn_mfma_f32_16x16x32_f16(a0, b, acc0, 0, 0, 0);
        acc1 = __builtin_amdgcn_mfma_f32_16x16x32_f16(a1, b, acc1, 0, 0, 0);
    }

    // Epilogue (R12/R13-validated map: tile row = q*4 + r, col = rf)
    const int n0 = nt * 16;
    #pragma unroll
    for (int i = 0; i < 2; ++i) {
        const int mt = i ? mt1 : mt0;
        const float4v acc = i ? acc1 : acc0;
        const int srow0 = mt * 16;
        if (srow0 < 2048) {
            const int b  = srow0 >> 8;
            const int sb = (srow0 & 255) + q * 4;
            float4 o = make_float4(exp2_sat(acc[0]*K2F), exp2_sat(acc[1]*K2F),
                                   exp2_sat(acc[2]*K2F), exp2_sat(acc[3]*K2F));
            *(float4*)(encT + (size_t)b * HD * SD + (size_t)(n0 + rf) * SD + sb) = o;
        } else {
            const int mrow = (srow0 - 2048) + q * 4;
            #pragma unroll
            for (int r = 0; r < 4; ++r)
                qryf[(size_t)(mrow + r) * HD + n0 + rf] = exp2_sat(acc[r] * K2F);
        }
    }
}

// ---------------- attn: exact R7 structure (48 µs timed) ----------------
__global__ __launch_bounds__(512) void attn_kernel(
    const float* __restrict__ enc,     // (B,S,H) raw
    const float* __restrict__ encT,    // (B,H,S) E_e
    const float* __restrict__ qryf,    // (B,T,H) E_q
    const float* __restrict__ v,       // (H)
    const int*   __restrict__ lens,    // (B)
    float* __restrict__ out)           // (B,T,H)
{
    __shared__ float qls[HD * 4];      // [j][t]  8 KB (E_q)
    __shared__ float pls[8 * 4 * 256]; // [w][t][s] partials 32 KB; aliased avred
    __shared__ float wls[4 * SD];      // [t][s] weights 4 KB

    const int blk = blockIdx.x;        // 0..511
    const int b   = blk >> 6;
    const int t0  = (blk & 63) * 4;
    const int tid = threadIdx.x;
    const int w   = tid >> 6;          // wave 0..7
    const int l   = tid & 63;

    {   // stage E_q transposed: qls[j*4+t]
        const float* qf = qryf + ((size_t)b * TD + t0) * HD;
        float4 qv;
        qv.x = qf[0 * HD + tid]; qv.y = qf[1 * HD + tid];
        qv.z = qf[2 * HD + tid]; qv.w = qf[3 * HD + tid];
        *(float4*)&qls[tid * 4] = qv;
    }
    __syncthreads();

    // ---- scores: wave w covers j in [w*64, w*64+64); lane owns s = 4l..4l+3 ----
    float a[4][4];
    #pragma unroll
    for (int t = 0; t < 4; ++t)
        #pragma unroll
        for (int c = 0; c < 4; ++c) a[t][c] = 0.0f;
    {
        const float* ep = encT + (size_t)b * HD * SD + (size_t)(w * 64) * SD + l * 4;
        const int jbase = w * 64;
        #pragma unroll 4
        for (int jj = 0; jj < 64; ++jj) {
            float4 e = *(const float4*)(ep + (size_t)jj * SD);  // E_e, coalesced
            float4 q4 = *(const float4*)&qls[(jbase + jj) * 4]; // E_q, broadcast
            float vj = v[jbase + jj];
            float ev[4] = {e.x, e.y, e.z, e.w};
            float qv[4] = {q4.x, q4.y, q4.z, q4.w};
            #pragma unroll
            for (int t = 0; t < 4; ++t)
                #pragma unroll
                for (int c = 0; c < 4; ++c) {
                    float p = fmaf(ev[c], qv[t], 1.0f);
                    a[t][c] = fmaf(vj, RCP(p), a[t][c]);
                }
        }
    }
    #pragma unroll
    for (int t = 0; t < 4; ++t)
        *(float4*)&pls[(w * 4 + t) * 256 + l * 4] = make_float4(a[t][0], a[t][1], a[t][2], a[t][3]);
    __syncthreads();

    // ---- combine 8 j-slices + masked softmax ----
    if (w < 4) {
        const int t = w;
        float p[4] = {0, 0, 0, 0};
        #pragma unroll
        for (int g = 0; g < 8; ++g) {
            float4 pp = *(const float4*)&pls[(g * 4 + t) * 256 + l * 4];
            p[0] += pp.x; p[1] += pp.y; p[2] += pp.z; p[3] += pp.w;
        }
        const int len = lens[b];
        const int s0 = l * 4;
        float sc[4];
        #pragma unroll
        for (int c = 0; c < 4; ++c)
            sc[c] = (s0 + c < len) ? -2.0f * p[c] : -INFINITY;
        float mx = fmaxf(fmaxf(sc[0], sc[1]), fmaxf(sc[2], sc[3]));
        #pragma unroll
        for (int off = 32; off; off >>= 1) mx = fmaxf(mx, __shfl_xor(mx, off));
        float ex[4]; float sum = 0.0f;
        #pragma unroll
        for (int c = 0; c < 4; ++c) { ex[c] = __expf(sc[c] - mx); sum += ex[c]; }
        #pragma unroll
        for (int off = 32; off; off >>= 1) sum += __shfl_xor(sum, off);
        const float inv = RCP(sum);
        *(float4*)&wls[t * SD + s0] = make_float4(ex[0]*inv, ex[1]*inv, ex[2]*inv, ex[3]*inv);
    }
    __syncthreads();

    // ---- AV: thread owns (h-float4, s-slice g); accumulates all 4 t ----
    const int g  = tid >> 7;
    const int h4 = (tid & 127) * 4;
    float* avred = pls;
    {
        const float* eb = enc + (size_t)b * SD * HD + h4;
        float4 o[4] = {{0,0,0,0},{0,0,0,0},{0,0,0,0},{0,0,0,0}};
        #pragma unroll 2
        for (int ss = 0; ss < 64; ++ss) {
            const int s = g * 64 + ss;
            float4 evv = *(const float4*)(eb + (size_t)s * HD);
            float wt[4];
            #pragma unroll
            for (int t = 0; t < 4; ++t) wt[t] = wls[t * SD + s];
            #pragma unroll
            for (int t = 0; t < 4; ++t) {
                o[t].x = fmaf(wt[t], evv.x, o[t].x);
                o[t].y = fmaf(wt[t], evv.y, o[t].y);
                o[t].z = fmaf(wt[t], evv.z, o[t].z);
                o[t].w = fmaf(wt[t], evv.w, o[t].w);
            }
        }
        #pragma unroll
        for (int t = 0; t < 4; ++t)
            *(float4*)&avred[(size_t)(g * 4 + t) * 512 + h4] = o[t];
    }
    __syncthreads();

    {
        const int t  = tid >> 7;
        const int hh = (tid & 127) * 4;
        float4 r = {0, 0, 0, 0};
        #pragma unroll
        for (int gg = 0; gg < 4; ++gg) {
            float4 xx = *(const float4*)&avred[(size_t)(gg * 4 + t) * 512 + hh];
            r.x += xx.x; r.y += xx.y; r.z += xx.z; r.w += xx.w;
        }
        *(float4*)(out + ((size_t)b * TD + t0 + t) * HD + hh) = r;
    }
}

extern "C" void kernel_launch(void* const* d_in, const int* in_sizes, int n_in,
                              void* d_out, int out_size, void* d_ws, size_t ws_size,
                              hipStream_t stream) {
    const float* query = (const float*)d_in[0];
    const float* enc   = (const float*)d_in[1];
    const int*   lens  = (const int*)d_in[2];
    const float* W_h   = (const float*)d_in[3];
    const float* W_s   = (const float*)d_in[4];
    const float* v     = (const float*)d_in[5];
    float* out = (float*)d_out;

    char* ws = (char*)d_ws;
    float*    encT = (float*)(ws);                        // 4 MB (B,H,S)  E_e
    float*    qryf = (float*)(ws + ((size_t)4  << 20));   // 4 MB (B,T,H)  E_q
    _Float16* Apk  = (_Float16*)(ws + ((size_t)8  << 20));// 4 MB packed A (256 tiles)
    _Float16* Bpk  = (_Float16*)(ws + ((size_t)12 << 20));// 1 MB packed B (64 tiles)

    pack_kernel<<<320, 256, 0, stream>>>(enc, query, W_h, W_s, Apk, Bpk);
    proj_kernel<<<1024, 256, 0, stream>>>(Apk, Bpk, encT, qryf);
    attn_kernel<<<512, 512, 0, stream>>>(enc, encT, qryf, v, lens, out);
}

// Round 15
// 122.038 us; speedup vs baseline: 1.3552x; 1.0002x over previous
//
#include <hip/hip_runtime.h>
#include <cstddef>
#include <math.h>

#define BD 8
#define TD 256
#define SD 256
#define HD 512
#define K2F 2.885390081777927f    // 2*log2(e): arg of exp2 for e^(2x)

#define EXP2(x) __builtin_amdgcn_exp2f(x)
#define RCP(x)  __builtin_amdgcn_rcpf(x)

typedef __attribute__((ext_vector_type(8))) _Float16 half8;
typedef __attribute__((ext_vector_type(4))) _Float16 half4;
typedef __attribute__((ext_vector_type(4))) float float4v;

// exp2 with arg clamped so E in [2^-80, 2^80]: products overflow to inf -> rcp -> 0,
// underflow to 0 -> r = 1; no inf*0 NaN path possible.
__device__ __forceinline__ float exp2_sat(float x) {
    return EXP2(fminf(fmaxf(x, -80.0f), 80.0f));
}

// ---------------- pack: fp32 -> fp16 in MFMA-fragment order (R14, proven) ----------------
#define CSTR 536
__global__ __launch_bounds__(256) void pack_kernel(
    const float* __restrict__ enc, const float* __restrict__ qry,
    const float* __restrict__ Wh,  const float* __restrict__ Ws,
    _Float16* __restrict__ Apk,    // 256 tiles (enc 0..127, qry 128..255)
    _Float16* __restrict__ Bpk)    // 64 tiles (Wh 0..31, Ws 32..63)
{
    __shared__ _Float16 lds[16 * CSTR];

    const int bid = blockIdx.x;          // 0..319
    const int tid = threadIdx.x;

    const float* src;
    _Float16* dst;
    if (bid < 128)      { src = enc + (size_t)bid * 16 * HD;         dst = Apk + (size_t)bid * 8192; }
    else if (bid < 256) { src = qry + (size_t)(bid - 128) * 16 * HD; dst = Apk + (size_t)bid * 8192; }
    else if (bid < 288) { src = Wh  + (size_t)(bid - 256) * 16 * HD; dst = Bpk + (size_t)(bid - 256) * 8192; }
    else                { src = Ws  + (size_t)(bid - 288) * 16 * HD; dst = Bpk + (size_t)(bid - 256) * 8192; }

    #pragma unroll
    for (int i = 0; i < 8; ++i) {
        const int flat = i * 1024 + tid * 4;
        float4 x = *(const float4*)(src + flat);
        const int row = flat >> 9, col = flat & 511;
        half4 h;
        h[0]=(_Float16)x.x; h[1]=(_Float16)x.y; h[2]=(_Float16)x.z; h[3]=(_Float16)x.w;
        *(half4*)&lds[row * CSTR + col] = h;
    }
    __syncthreads();

    #pragma unroll
    for (int j = 0; j < 4; ++j) {
        const int r  = j * 256 + tid;
        const int ks = r >> 6, l = r & 63;
        const int rf = l & 15, q = l >> 4;
        half8 h = *(const half8*)&lds[rf * CSTR + ks * 32 + q * 8];
        *(half8*)(dst + (size_t)r * 8) = h;
    }
}

// ---------------- proj: fragment-direct MFMA, 1KB-contiguous loads (R14, proven) ----------------
__global__ __launch_bounds__(256) void proj_kernel(
    const _Float16* __restrict__ Apk, const _Float16* __restrict__ Bpk,
    float* __restrict__ encT, float* __restrict__ qryf)
{
    const int bid = blockIdx.x;          // 0..1023
    const int tid = threadIdx.x;
    const int l   = tid & 63;
    const int w   = tid >> 6;            // wave 0..3
    const int rf  = l & 15;
    const int q   = l >> 4;

    const int nt = bid & 31;             // n-tile 0..31
    const int mg = bid >> 5;             // m-group 0..31
    const int mt0 = mg * 8 + w * 2;      // m-tiles (0..255)
    const int mt1 = mt0 + 1;

    const _Float16* A0 = Apk + (size_t)mt0 * 8192 + l * 8;
    const _Float16* A1 = Apk + (size_t)mt1 * 8192 + l * 8;
    const _Float16* Bp = Bpk + (size_t)(((mt0 >= 128) ? 32 : 0) + nt) * 8192 + l * 8;

    float4v acc0 = {0,0,0,0}, acc1 = {0,0,0,0};

    #pragma unroll 4
    for (int ks = 0; ks < 16; ++ks) {
        half8 a0 = *(const half8*)(A0 + (size_t)ks * 512);
        half8 a1 = *(const half8*)(A1 + (size_t)ks * 512);
        half8 b  = *(const half8*)(Bp + (size_t)ks * 512);
        acc0 = __builtin_amdgcn_mfma_f32_16x16x32_f16(a0, b, acc0, 0, 0, 0);
        acc1 = __builtin_amdgcn_mfma_f32_16x16x32_f16(a1, b, acc1, 0, 0, 0);
    }

    const int n0 = nt * 16;
    #pragma unroll
    for (int i = 0; i < 2; ++i) {
        const int mt = i ? mt1 : mt0;
        const float4v acc = i ? acc1 : acc0;
        const int srow0 = mt * 16;
        if (srow0 < 2048) {
            const int b  = srow0 >> 8;
            const int sb = (srow0 & 255) + q * 4;
            float4 o = make_float4(exp2_sat(acc[0]*K2F), exp2_sat(acc[1]*K2F),
                                   exp2_sat(acc[2]*K2F), exp2_sat(acc[3]*K2F));
            *(float4*)(encT + (size_t)b * HD * SD + (size_t)(n0 + rf) * SD + sb) = o;
        } else {
            const int mrow = (srow0 - 2048) + q * 4;
            #pragma unroll
            for (int r = 0; r < 4; ++r)
                qryf[(size_t)(mrow + r) * HD + n0 + rf] = exp2_sat(acc[r] * K2F);
        }
    }
}

// ---------------- attn: R7 math, 28 KB LDS (two-stage partials -> 4+ blocks/CU) ----------------
__global__ __launch_bounds__(512) void attn_kernel(
    const float* __restrict__ enc,     // (B,S,H) raw
    const float* __restrict__ encT,    // (B,H,S) E_e
    const float* __restrict__ qryf,    // (B,T,H) E_q
    const float* __restrict__ v,       // (H)
    const int*   __restrict__ lens,    // (B)
    float* __restrict__ out)           // (B,T,H)
{
    __shared__ float qls[HD * 4];      // [j][t]  8 KB (E_q)
    __shared__ float pls[4 * 4 * 256]; // [slice(4)][t(4)][s(256)] 16 KB; aliased avred
    __shared__ float wls[4 * SD];      // [t][s] weights 4 KB          -> total 28 KB

    const int blk = blockIdx.x;        // 0..511
    const int b   = blk >> 6;
    const int t0  = (blk & 63) * 4;
    const int tid = threadIdx.x;
    const int w   = tid >> 6;          // wave 0..7
    const int l   = tid & 63;

    {   // stage E_q transposed: qls[j*4+t]
        const float* qf = qryf + ((size_t)b * TD + t0) * HD;
        float4 qv;
        qv.x = qf[0 * HD + tid]; qv.y = qf[1 * HD + tid];
        qv.z = qf[2 * HD + tid]; qv.w = qf[3 * HD + tid];
        *(float4*)&qls[tid * 4] = qv;
    }
    __syncthreads();

    // ---- scores: wave w covers j in [w*64, w*64+64); lane owns s = 4l..4l+3 ----
    float a[4][4];
    #pragma unroll
    for (int t = 0; t < 4; ++t)
        #pragma unroll
        for (int c = 0; c < 4; ++c) a[t][c] = 0.0f;
    {
        const float* ep = encT + (size_t)b * HD * SD + (size_t)(w * 64) * SD + l * 4;
        const int jbase = w * 64;
        #pragma unroll 4
        for (int jj = 0; jj < 64; ++jj) {
            float4 e = *(const float4*)(ep + (size_t)jj * SD);  // E_e, coalesced
            float4 q4 = *(const float4*)&qls[(jbase + jj) * 4]; // E_q, broadcast
            float vj = v[jbase + jj];
            float ev[4] = {e.x, e.y, e.z, e.w};
            float qv[4] = {q4.x, q4.y, q4.z, q4.w};
            #pragma unroll
            for (int t = 0; t < 4; ++t)
                #pragma unroll
                for (int c = 0; c < 4; ++c) {
                    float p = fmaf(ev[c], qv[t], 1.0f);
                    a[t][c] = fmaf(vj, RCP(p), a[t][c]);
                }
        }
    }
    // two-stage partial accumulate (R10-validated): waves 0-3 write, 4-7 add
    if (w < 4) {
        #pragma unroll
        for (int t = 0; t < 4; ++t)
            *(float4*)&pls[(w * 4 + t) * 256 + l * 4] =
                make_float4(a[t][0], a[t][1], a[t][2], a[t][3]);
    }
    __syncthreads();
    if (w >= 4) {
        #pragma unroll
        for (int t = 0; t < 4; ++t) {
            float4 c4 = *(const float4*)&pls[((w - 4) * 4 + t) * 256 + l * 4];
            c4.x += a[t][0]; c4.y += a[t][1]; c4.z += a[t][2]; c4.w += a[t][3];
            *(float4*)&pls[((w - 4) * 4 + t) * 256 + l * 4] = c4;
        }
    }
    __syncthreads();

    // ---- combine 4 slices + masked softmax: wave t<4 handles t; lane owns 4 s ----
    if (w < 4) {
        const int t = w;
        float p[4] = {0, 0, 0, 0};
        #pragma unroll
        for (int g = 0; g < 4; ++g) {
            float4 pp = *(const float4*)&pls[(g * 4 + t) * 256 + l * 4];
            p[0] += pp.x; p[1] += pp.y; p[2] += pp.z; p[3] += pp.w;
        }
        const int len = lens[b];
        const int s0 = l * 4;
        float sc[4];
        #pragma unroll
        for (int c = 0; c < 4; ++c)
            sc[c] = (s0 + c < len) ? -2.0f * p[c] : -INFINITY;
        float mx = fmaxf(fmaxf(sc[0], sc[1]), fmaxf(sc[2], sc[3]));
        #pragma unroll
        for (int off = 32; off; off >>= 1) mx = fmaxf(mx, __shfl_xor(mx, off));
        float ex[4]; float sum = 0.0f;
        #pragma unroll
        for (int c = 0; c < 4; ++c) { ex[c] = __expf(sc[c] - mx); sum += ex[c]; }
        #pragma unroll
        for (int off = 32; off; off >>= 1) sum += __shfl_xor(sum, off);
        const float inv = RCP(sum);
        *(float4*)&wls[t * SD + s0] = make_float4(ex[0]*inv, ex[1]*inv, ex[2]*inv, ex[3]*inv);
    }
    __syncthreads();

    // ---- AV: thread owns (h-float4, s-slice sg); accumulates all 4 t; two-stage reduce ----
    const int sg = tid >> 7;           // 0..3 (wave-uniform)
    const int h4 = (tid & 127) * 4;
    float* avred = pls;                // [slice(2)][t(4)][h(512)] = 4096 floats
    float4 o[4] = {{0,0,0,0},{0,0,0,0},{0,0,0,0},{0,0,0,0}};
    {
        const float* eb = enc + (size_t)b * SD * HD + h4;
        #pragma unroll 2
        for (int ss = 0; ss < 64; ++ss) {
            const int s = sg * 64 + ss;
            float4 evv = *(const float4*)(eb + (size_t)s * HD);
            float wt[4];
            #pragma unroll
            for (int t = 0; t < 4; ++t) wt[t] = wls[t * SD + s];
            #pragma unroll
            for (int t = 0; t < 4; ++t) {
                o[t].x = fmaf(wt[t], evv.x, o[t].x);
                o[t].y = fmaf(wt[t], evv.y, o[t].y);
                o[t].z = fmaf(wt[t], evv.z, o[t].z);
                o[t].w = fmaf(wt[t], evv.w, o[t].w);
            }
        }
    }
    if (sg < 2) {
        #pragma unroll
        for (int t = 0; t < 4; ++t)
            *(float4*)&avred[(size_t)(sg * 4 + t) * 512 + h4] = o[t];
    }
    __syncthreads();
    if (sg >= 2) {
        #pragma unroll
        for (int t = 0; t < 4; ++t) {
            float4 c4 = *(const float4*)&avred[(size_t)((sg - 2) * 4 + t) * 512 + h4];
            c4.x += o[t].x; c4.y += o[t].y; c4.z += o[t].z; c4.w += o[t].w;
            *(float4*)&avred[(size_t)((sg - 2) * 4 + t) * 512 + h4] = c4;
        }
    }
    __syncthreads();

    // final reduce + store: thread owns (t = tid>>7, h-float4)
    {
        const int t  = tid >> 7;
        const int hh = (tid & 127) * 4;
        float4 x0 = *(const float4*)&avred[(size_t)(0 * 4 + t) * 512 + hh];
        float4 x1 = *(const float4*)&avred[(size_t)(1 * 4 + t) * 512 + hh];
        float4 r = make_float4(x0.x + x1.x, x0.y + x1.y, x0.z + x1.z, x0.w + x1.w);
        *(float4*)(out + ((size_t)b * TD + t0 + t) * HD + hh) = r;
    }
}

extern "C" void kernel_launch(void* const* d_in, const int* in_sizes, int n_in,
                              void* d_out, int out_size, void* d_ws, size_t ws_size,
                              hipStream_t stream) {
    const float* query = (const float*)d_in[0];
    const float* enc   = (const float*)d_in[1];
    const int*   lens  = (const int*)d_in[2];
    const float* W_h   = (const float*)d_in[3];
    const float* W_s   = (const float*)d_in[4];
    const float* v     = (const float*)d_in[5];
    float* out = (float*)d_out;

    char* ws = (char*)d_ws;
    float*    encT = (float*)(ws);                        // 4 MB (B,H,S)  E_e
    float*    qryf = (float*)(ws + ((size_t)4  << 20));   // 4 MB (B,T,H)  E_q
    _Float16* Apk  = (_Float16*)(ws + ((size_t)8  << 20));// 4 MB packed A (256 tiles)
    _Float16* Bpk  = (_Float16*)(ws + ((size_t)12 << 20));// 1 MB packed B (64 tiles)

    pack_kernel<<<320, 256, 0, stream>>>(enc, query, W_h, W_s, Apk, Bpk);
    proj_kernel<<<1024, 256, 0, stream>>>(Apk, Bpk, encT, qryf);
    attn_kernel<<<512, 512, 0, stream>>>(enc, encT, qryf, v, lens, out);
}